// Round 2
// baseline (220.590 us; speedup 1.0000x reference)
//
#include <hip/hip_runtime.h>

// Problem constants
#define N_B   4
#define N_T   16
#define N_Y   256
#define N_X   256
#define PIX   65536        // N_Y*N_X
#define BATCHF 7340032     // floats per batch input = 112*65536

// Output float offsets
#define M_BASE     4194304
#define H_BASE     12582912
#define TAU_BASE   29360128

typedef float f4 __attribute__((ext_vector_type(4)));

__device__ __forceinline__ float sp10(float x) {
    // softplus(10x)/10, numerically stable
    float z = 10.0f * x;
    float r = fmaxf(z, 0.0f) + log1pf(__expf(-fabsf(z)));
    return r * 0.1f;
}

__device__ __forceinline__ f4 ntload(const float* p) {
    return __builtin_nontemporal_load(reinterpret_cast<const f4*>(p));
}
__device__ __forceinline__ void ntstore(float* p, f4 v) {
    __builtin_nontemporal_store(v, reinterpret_cast<f4*>(p));
}

__global__ __launch_bounds__(256)
void decode_param_kernel(const float* __restrict__ p, float* __restrict__ out) {
    // LDS: per-t rows of 64 x-values, padded row stride 68 floats
    __shared__ float l00[N_T][68];
    __shared__ float l01[N_T][68];
    __shared__ float l11[N_T][68];

    const int bid = blockIdx.x;
    const int tid = threadIdx.x;

    if (bid < 4096) {
        // ---- H blocks: one (b, y, 64-wide x tile) each ----
        const int xt = bid & 3;          // x tile 0..3
        const int y  = (bid >> 2) & 255; // row
        const int b  = bid >> 10;        // batch
        const int t  = tid >> 4;         // 0..15
        const int xq = tid & 15;         // 0..15 -> x-local quad

        const long inbase = (long)b * BATCHF + (long)y * N_X + xt * 64 + xq * 4;
        const f4 g4  = ntload(p + inbase + (long)(48 + t) * PIX);
        const f4 vx4 = ntload(p + inbase + (long)(64 + t) * PIX);
        const f4 vy4 = ntload(p + inbase + (long)(80 + t) * PIX);

        f4 h00, h01, h11;
        {
            f4 g;
            g.x = sp10(g4.x); g.y = sp10(g4.y); g.z = sp10(g4.z); g.w = sp10(g4.w);
            h00 = g + vx4 * vx4;
            h01 = vx4 * vy4;
            h11 = g + vy4 * vy4;
        }
        *reinterpret_cast<f4*>(&l00[t][xq * 4]) = h00;
        *reinterpret_cast<f4*>(&l01[t][xq * 4]) = h01;
        *reinterpret_cast<f4*>(&l11[t][xq * 4]) = h11;
        __syncthreads();

        // phase 2: each thread emits one float4 along t for one x
        const int xl = tid >> 2;          // 0..63 (x local)
        const int tq = (tid & 3) * 4;     // 0,4,8,12

        f4 o00, o01, o11;
        o00.x = l00[tq + 0][xl]; o00.y = l00[tq + 1][xl];
        o00.z = l00[tq + 2][xl]; o00.w = l00[tq + 3][xl];
        o01.x = l01[tq + 0][xl]; o01.y = l01[tq + 1][xl];
        o01.z = l01[tq + 2][xl]; o01.w = l01[tq + 3][xl];
        o11.x = l11[tq + 0][xl]; o11.y = l11[tq + 1][xl];
        o11.z = l11[tq + 2][xl]; o11.w = l11[tq + 3][xl];

        const long outoff = (long)H_BASE + (long)b * 4194304 + (long)y * 4096
                          + xt * 1024 + xl * 16 + tq;
        ntstore(out + outoff,           o00);  // H00
        ntstore(out + outoff + 1048576, o01);  // H01
        ntstore(out + outoff + 2097152, o01);  // H10 (== H01)
        ntstore(out + outoff + 3145728, o11);  // H11
    } else {
        // ---- elementwise blocks: kappa / m-copy / tau ----
        // 16 jobs of 2^18 float4 each: job = b*4 + kind
        const long j   = (long)(bid - 4096) * 256 + tid;  // 0 .. 4194303
        const int job  = (int)(j >> 18);
        const long r   = j & 262143;
        const int b    = job >> 2;
        const int kind = job & 3;

        const long inb = (long)b * (BATCHF / 4);
        long in4, out4;
        bool do_sp;
        if (kind == 0)      { in4 = inb;           out4 = (long)b * 262144;                 do_sp = true;  } // kappa
        else if (kind == 1) { in4 = inb + 262144;  out4 = M_BASE / 4 + (long)b * 524288;    do_sp = false; } // m c=0
        else if (kind == 2) { in4 = inb + 524288;  out4 = M_BASE / 4 + 262144 + (long)b * 524288; do_sp = false; } // m c=1
        else                { in4 = inb + 1572864; out4 = TAU_BASE / 4 + (long)b * 262144;  do_sp = true;  } // tau

        f4 v = ntload(p + (in4 + r) * 4);
        if (do_sp) {
            v.x = sp10(v.x); v.y = sp10(v.y); v.z = sp10(v.z); v.w = sp10(v.w);
        }
        ntstore(out + (out4 + r) * 4, v);
    }
}

extern "C" void kernel_launch(void* const* d_in, const int* in_sizes, int n_in,
                              void* d_out, int out_size, void* d_ws, size_t ws_size,
                              hipStream_t stream) {
    const float* p = (const float*)d_in[0];
    float* out = (float*)d_out;
    // 4096 H blocks + 16384 elementwise blocks
    decode_param_kernel<<<20480, 256, 0, stream>>>(p, out);
}

// Round 3
// 211.494 us; speedup vs baseline: 1.0430x; 1.0430x over previous
//
#include <hip/hip_runtime.h>

// Problem constants
#define N_B   4
#define N_T   16
#define N_Y   256
#define N_X   256
#define PIX   65536        // N_Y*N_X
#define BATCHF 7340032     // floats per batch input = 112*65536

// Output float offsets
#define M_BASE     4194304
#define H_BASE     12582912
#define TAU_BASE   29360128

typedef float f4 __attribute__((ext_vector_type(4)));

__device__ __forceinline__ float sp10(float x) {
    // softplus(10x)/10 via fast HW transcendentals:
    // max(z,0) + log(1+exp(-|z|)); abs err ~1e-6 << 0.6 threshold
    float z = 10.0f * x;
    float e = __expf(-fabsf(z));
    float r = fmaxf(z, 0.0f) + __logf(1.0f + e);
    return r * 0.1f;
}

__device__ __forceinline__ f4 ntload(const float* p) {
    return __builtin_nontemporal_load(reinterpret_cast<const f4*>(p));
}
__device__ __forceinline__ void ntstore(float* p, f4 v) {
    __builtin_nontemporal_store(v, reinterpret_cast<f4*>(p));
}

__global__ __launch_bounds__(256)
void decode_param_kernel(const float* __restrict__ p, float* __restrict__ out) {
    __shared__ float l00[N_T][68];
    __shared__ float l01[N_T][68];
    __shared__ float l11[N_T][68];

    const int bid = blockIdx.x;
    const int tid = threadIdx.x;

    if (bid < 4096) {
        // ---- H blocks: one (b, y, 64-wide x tile) each ----
        const int xt = bid & 3;          // x tile 0..3
        const int y  = (bid >> 2) & 255; // row
        const int b  = bid >> 10;        // batch
        const int t  = tid >> 4;         // 0..15
        const int xq = tid & 15;         // 0..15 -> x-local quad

        const long inbase = (long)b * BATCHF + (long)y * N_X + xt * 64 + xq * 4;
        const f4 g4  = ntload(p + inbase + (long)(48 + t) * PIX);
        const f4 vx4 = ntload(p + inbase + (long)(64 + t) * PIX);
        const f4 vy4 = ntload(p + inbase + (long)(80 + t) * PIX);

        f4 h00, h01, h11;
        {
            f4 g;
            g.x = sp10(g4.x); g.y = sp10(g4.y); g.z = sp10(g4.z); g.w = sp10(g4.w);
            h00 = g + vx4 * vx4;
            h01 = vx4 * vy4;
            h11 = g + vy4 * vy4;
        }
        *reinterpret_cast<f4*>(&l00[t][xq * 4]) = h00;
        *reinterpret_cast<f4*>(&l01[t][xq * 4]) = h01;
        *reinterpret_cast<f4*>(&l11[t][xq * 4]) = h11;
        __syncthreads();

        // phase 2: each thread emits one float4 along t for one x
        const int xl = tid >> 2;          // 0..63 (x local)
        const int tq = (tid & 3) * 4;     // 0,4,8,12

        f4 o00, o01, o11;
        o00.x = l00[tq + 0][xl]; o00.y = l00[tq + 1][xl];
        o00.z = l00[tq + 2][xl]; o00.w = l00[tq + 3][xl];
        o01.x = l01[tq + 0][xl]; o01.y = l01[tq + 1][xl];
        o01.z = l01[tq + 2][xl]; o01.w = l01[tq + 3][xl];
        o11.x = l11[tq + 0][xl]; o11.y = l11[tq + 1][xl];
        o11.z = l11[tq + 2][xl]; o11.w = l11[tq + 3][xl];

        const long outoff = (long)H_BASE + (long)b * 4194304 + (long)y * 4096
                          + xt * 1024 + xl * 16 + tq;
        ntstore(out + outoff,           o00);  // H00
        ntstore(out + outoff + 1048576, o01);  // H01
        ntstore(out + outoff + 2097152, o01);  // H10 (== H01)
        ntstore(out + outoff + 3145728, o11);  // H11
    } else {
        // ---- elementwise blocks: kappa / m-copy / tau, 2 float4 per thread ----
        // 16 jobs of 2^18 float4; each thread does r and r+131072 within one job
        const long j   = (long)(bid - 4096) * 256 + tid;  // 0 .. 2097151
        const int job  = (int)(j >> 17);
        const long r   = j & 131071;
        const int b    = job >> 2;
        const int kind = job & 3;

        const long inb = (long)b * (BATCHF / 4);
        long in4, out4;
        bool do_sp;
        if (kind == 0)      { in4 = inb;           out4 = (long)b * 262144;                 do_sp = true;  } // kappa
        else if (kind == 1) { in4 = inb + 262144;  out4 = M_BASE / 4 + (long)b * 524288;    do_sp = false; } // m c=0
        else if (kind == 2) { in4 = inb + 524288;  out4 = M_BASE / 4 + 262144 + (long)b * 524288; do_sp = false; } // m c=1
        else                { in4 = inb + 1572864; out4 = TAU_BASE / 4 + (long)b * 262144;  do_sp = true;  } // tau

        f4 v0 = ntload(p + (in4 + r) * 4);
        f4 v1 = ntload(p + (in4 + r + 131072) * 4);
        if (do_sp) {
            v0.x = sp10(v0.x); v0.y = sp10(v0.y); v0.z = sp10(v0.z); v0.w = sp10(v0.w);
            v1.x = sp10(v1.x); v1.y = sp10(v1.y); v1.z = sp10(v1.z); v1.w = sp10(v1.w);
        }
        ntstore(out + (out4 + r) * 4, v0);
        ntstore(out + (out4 + r + 131072) * 4, v1);
    }
}

extern "C" void kernel_launch(void* const* d_in, const int* in_sizes, int n_in,
                              void* d_out, int out_size, void* d_ws, size_t ws_size,
                              hipStream_t stream) {
    const float* p = (const float*)d_in[0];
    float* out = (float*)d_out;
    // 4096 H blocks + 8192 elementwise blocks
    decode_param_kernel<<<12288, 256, 0, stream>>>(p, out);
}

// Round 4
// 208.791 us; speedup vs baseline: 1.0565x; 1.0129x over previous
//
#include <hip/hip_runtime.h>

// Problem constants
#define N_B   4
#define N_T   16
#define N_Y   256
#define N_X   256
#define PIX   65536        // N_Y*N_X
#define BATCHF 7340032     // floats per batch input = 112*65536

// Output float offsets
#define M_BASE     4194304
#define H_BASE     12582912
#define TAU_BASE   29360128

typedef float f4 __attribute__((ext_vector_type(4)));

__device__ __forceinline__ float sp10(float x) {
    // softplus(10x)/10 via HW transcendentals (v_exp_f32 / v_log_f32)
    float z = 10.0f * x;
    float e = __expf(-fabsf(z));
    float r = fmaxf(z, 0.0f) + __logf(1.0f + e);
    return r * 0.1f;
}

__device__ __forceinline__ f4 ntload(const float* p) {
    return __builtin_nontemporal_load(reinterpret_cast<const f4*>(p));
}
__device__ __forceinline__ void ntstore(float* p, f4 v) {
    __builtin_nontemporal_store(v, reinterpret_cast<f4*>(p));
}

__device__ __forceinline__ f4 sp4(f4 v) {
    f4 r;
    r.x = sp10(v.x); r.y = sp10(v.y); r.z = sp10(v.z); r.w = sp10(v.w);
    return r;
}

__global__ __launch_bounds__(256)
void decode_param_kernel(const float* __restrict__ p, float* __restrict__ out) {
    // 128-x tile: rows of 128 + 4 pad (row stride 132 floats).
    // Phase-1 float4 writes; phase-2 column b32 reads are 2-way conflicts (free).
    __shared__ float l00[N_T][132];
    __shared__ float l01[N_T][132];
    __shared__ float l11[N_T][132];

    const int bid = blockIdx.x;
    const int tid = threadIdx.x;

    if (bid < 2048) {
        // ---- H blocks: one (b, y, 128-wide x tile) each ----
        const int xt = bid & 1;          // x tile 0..1
        const int y  = (bid >> 1) & 255; // row
        const int b  = bid >> 9;         // batch
        const int t  = tid >> 4;         // 0..15
        const int xq = tid & 15;         // quad index; handles xq*4 and xq*4+64

        const long inbase = (long)b * BATCHF + (long)y * N_X + xt * 128 + xq * 4;
        const float* pg  = p + inbase + (long)(48 + t) * PIX;
        const float* pvx = p + inbase + (long)(64 + t) * PIX;
        const float* pvy = p + inbase + (long)(80 + t) * PIX;

        f4 g0  = ntload(pg);       f4 g1  = ntload(pg + 64);
        f4 vx0 = ntload(pvx);      f4 vx1 = ntload(pvx + 64);
        f4 vy0 = ntload(pvy);      f4 vy1 = ntload(pvy + 64);

        g0 = sp4(g0);              g1 = sp4(g1);

        *reinterpret_cast<f4*>(&l00[t][xq * 4])      = g0 + vx0 * vx0;
        *reinterpret_cast<f4*>(&l00[t][xq * 4 + 64]) = g1 + vx1 * vx1;
        *reinterpret_cast<f4*>(&l01[t][xq * 4])      = vx0 * vy0;
        *reinterpret_cast<f4*>(&l01[t][xq * 4 + 64]) = vx1 * vy1;
        *reinterpret_cast<f4*>(&l11[t][xq * 4])      = g0 + vy0 * vy0;
        *reinterpret_cast<f4*>(&l11[t][xq * 4 + 64]) = g1 + vy1 * vy1;
        __syncthreads();

        // phase 2: thread handles x-values xl and xl+64, one t-quad tq
        const int xl = tid >> 2;          // 0..63
        const int tq = (tid & 3) * 4;     // 0,4,8,12

        f4 a00, a01, a11, b00, b01, b11;
        a00.x = l00[tq+0][xl];    a00.y = l00[tq+1][xl];
        a00.z = l00[tq+2][xl];    a00.w = l00[tq+3][xl];
        b00.x = l00[tq+0][xl+64]; b00.y = l00[tq+1][xl+64];
        b00.z = l00[tq+2][xl+64]; b00.w = l00[tq+3][xl+64];
        a01.x = l01[tq+0][xl];    a01.y = l01[tq+1][xl];
        a01.z = l01[tq+2][xl];    a01.w = l01[tq+3][xl];
        b01.x = l01[tq+0][xl+64]; b01.y = l01[tq+1][xl+64];
        b01.z = l01[tq+2][xl+64]; b01.w = l01[tq+3][xl+64];
        a11.x = l11[tq+0][xl];    a11.y = l11[tq+1][xl];
        a11.z = l11[tq+2][xl];    a11.w = l11[tq+3][xl];
        b11.x = l11[tq+0][xl+64]; b11.y = l11[tq+1][xl+64];
        b11.z = l11[tq+2][xl+64]; b11.w = l11[tq+3][xl+64];

        // out index: H_BASE + ((b*4 + comp)*65536 + y*256 + x)*16 + t
        const long outoff = (long)H_BASE + (long)b * 4194304 + (long)y * 4096
                          + xt * 2048 + xl * 16 + tq;
        ntstore(out + outoff,                  a00);
        ntstore(out + outoff + 1024,           b00);
        ntstore(out + outoff + 1048576,        a01);  // H01
        ntstore(out + outoff + 1048576 + 1024, b01);
        ntstore(out + outoff + 2097152,        a01);  // H10 == H01
        ntstore(out + outoff + 2097152 + 1024, b01);
        ntstore(out + outoff + 3145728,        a11);
        ntstore(out + outoff + 3145728 + 1024, b11);
    } else {
        // ---- elementwise blocks: kappa / m-copy / tau, 2 float4 per thread ----
        const long j   = (long)(bid - 2048) * 256 + tid;  // 0 .. 2097151
        const int job  = (int)(j >> 17);
        const long r   = j & 131071;
        const int b    = job >> 2;
        const int kind = job & 3;

        const long inb = (long)b * (BATCHF / 4);
        long in4, out4;
        bool do_sp;
        if (kind == 0)      { in4 = inb;           out4 = (long)b * 262144;                 do_sp = true;  } // kappa
        else if (kind == 1) { in4 = inb + 262144;  out4 = M_BASE / 4 + (long)b * 524288;    do_sp = false; } // m c=0
        else if (kind == 2) { in4 = inb + 524288;  out4 = M_BASE / 4 + 262144 + (long)b * 524288; do_sp = false; } // m c=1
        else                { in4 = inb + 1572864; out4 = TAU_BASE / 4 + (long)b * 262144;  do_sp = true;  } // tau

        f4 v0 = ntload(p + (in4 + r) * 4);
        f4 v1 = ntload(p + (in4 + r + 131072) * 4);
        if (do_sp) { v0 = sp4(v0); v1 = sp4(v1); }
        ntstore(out + (out4 + r) * 4, v0);
        ntstore(out + (out4 + r + 131072) * 4, v1);
    }
}

extern "C" void kernel_launch(void* const* d_in, const int* in_sizes, int n_in,
                              void* d_out, int out_size, void* d_ws, size_t ws_size,
                              hipStream_t stream) {
    const float* p = (const float*)d_in[0];
    float* out = (float*)d_out;
    // 2048 H blocks + 8192 elementwise blocks
    decode_param_kernel<<<10240, 256, 0, stream>>>(p, out);
}